// Round 16
// baseline (424.836 us; speedup 1.0000x reference)
//
#include <hip/hip_runtime.h>
#include <math.h>

typedef __attribute__((ext_vector_type(8))) short short8;
typedef __attribute__((ext_vector_type(4))) float f32x4;
typedef __attribute__((ext_vector_type(2))) unsigned int u32x2;
typedef __attribute__((ext_vector_type(4))) unsigned int u32x4;

#define E_NUM 16
constexpr int CAPS[E_NUM] = {1024,512,1024,256,1024,512,128,1024,512,1024,256,512,1024,128,64,512};
constexpr int OFFS[E_NUM] = {0,1024,1536,2560,2816,3840,4352,4480,5504,6016,7040,7296,7808,8832,8960,9024};
constexpr int cdiv_(int a, int b){ return (a + b - 1) / b; }
constexpr int ilog2_(int v){ int l = 0; while ((1 << l) < v) ++l; return l; }

__device__ __forceinline__ unsigned int cvt_pk_bf16(float a, float b){
  unsigned int r;
  asm("v_cvt_pk_bf16_f32 %0, %1, %2" : "=v"(r) : "v"(a), "v"(b));
  return r;
}

typedef __attribute__((address_space(1))) const unsigned char gas_u8;
typedef __attribute__((address_space(3))) unsigned char las_u8;
__device__ __forceinline__ void gl_lds16(const void* g, void* l){
  __builtin_amdgcn_global_load_lds((gas_u8*)g, (las_u8*)l, 16, 0, 0);
}

// fp32 -> bf16 (RNE), 8 elems/thread, grid-stride (used for x and W2)
__global__ __launch_bounds__(256) void cvt_bf16_kernel(const float* __restrict__ x,
                                                       unsigned short* __restrict__ xb, int n8)
{
  int i = blockIdx.x * blockDim.x + threadIdx.x;
  const int stride = gridDim.x * blockDim.x;
  for (; i < n8; i += stride) {
    f32x4 a = *reinterpret_cast<const f32x4*>(x + (size_t)i * 8);
    f32x4 b = *reinterpret_cast<const f32x4*>(x + (size_t)i * 8 + 4);
    u32x2 lo, hi;
    lo[0] = cvt_pk_bf16(a[0], a[1]); lo[1] = cvt_pk_bf16(a[2], a[3]);
    hi[0] = cvt_pk_bf16(b[0], b[1]); hi[1] = cvt_pk_bf16(b[2], b[3]);
    *reinterpret_cast<u32x2*>(xb + (size_t)i * 8)     = lo;
    *reinterpret_cast<u32x2*>(xb + (size_t)i * 8 + 4) = hi;
  }
}

// ===================== G1: 256x256, 512 thr, 3-buf counted-vmcnt (FROZEN) ===========
template<int NDIM, int KDIM, int LOG_GN, int NWG>
__global__ __launch_bounds__(512, 2)
void g1_gemm256(const unsigned short* __restrict__ Ah, const float* __restrict__ W,
                const float* __restrict__ bias, unsigned short* __restrict__ Oh)
{
  constexpr int A_BYTES = 256 * 64;
  constexpr int B_BYTES = 256 * 128;
  constexpr int BUF  = A_BYTES + B_BYTES;   // 48 KB
  constexpr int GN   = 1 << LOG_GN;
  constexpr int NTT  = KDIM / 32;
  static_assert(NWG % 8 == 0);
  static_assert(NTT >= 3);

  __shared__ __align__(16) char smem[3 * BUF];   // 144 KB

  const int tid  = threadIdx.x;
  const int braw = blockIdx.x;
  const int tt = (braw & 7) * (NWG / 8) + (braw >> 3);

  int m0 = 0, n0 = 0, Me = 0, tok0 = 0;
  size_t wbase = 0, bbase = 0;
  {
    int acc0 = 0;
    #pragma unroll
    for (int i = 0; i < E_NUM; ++i) {
      const int mt  = cdiv_(CAPS[i], 256);
      const int lmt = ilog2_(mt);
      const int nb  = mt * (NDIM / 256);
      if (tt >= acc0 && tt < acc0 + nb) {
        const int loc = tt - acc0;
        const int g   = loc >> (lmt + LOG_GN);
        const int rem = loc & ((mt << LOG_GN) - 1);
        m0   = (rem >> LOG_GN) * 256;
        n0   = ((g << LOG_GN) | (rem & (GN - 1))) * 256;
        Me   = CAPS[i];
        tok0 = OFFS[i];
        wbase = (size_t)i * NDIM * KDIM;
        bbase = (size_t)i * NDIM;
      }
      acc0 += nb;
    }
  }
  const float* Wb = W + wbase;

  const int lane = tid & 63;
  const int wv   = tid >> 6;

  auto stageA = [&](int buf, int kt) {
    const unsigned short* Ag = Ah + (size_t)(tok0 + m0) * KDIM + kt * 32;
    char* dst0 = smem + buf * BUF;
    #pragma unroll
    for (int j = 0; j < 2; ++j) {
      const int rbase = j * 128 + wv * 16;
      const int r     = rbase + (lane >> 2);
      const int blk   = (lane & 3) ^ (r & 3);
      gl_lds16((const void*)(Ag + (size_t)r * KDIM + blk * 8), (void*)(dst0 + rbase * 64));
    }
  };
  auto stageB = [&](int buf, int kt) {
    const float* Bg = Wb + (size_t)n0 * KDIM + kt * 32;
    char* dst0 = smem + buf * BUF + A_BYTES;
    #pragma unroll
    for (int j = 0; j < 4; ++j) {
      const int rbase = j * 64 + wv * 8;
      const int r     = rbase + (lane >> 3);
      const int blk   = (lane & 7) ^ (r & 7);
      gl_lds16((const void*)(Bg + (size_t)r * KDIM + blk * 4), (void*)(dst0 + rbase * 128));
    }
  };

  const int wm   = (wv >> 2) * 128;
  const int wn   = (wv & 3) * 64;
  const int lrow = lane & 15;
  const int pa0  = (((lane >> 4) ^ (lane & 3)) << 4);
  const int pb0  = ((((lane >> 4) << 1) ^ (lane & 7)) << 4);

  f32x4 acc_[8][4];
  #pragma unroll
  for (int i = 0; i < 8; ++i)
    #pragma unroll
    for (int j = 0; j < 4; ++j)
      acc_[i][j] = (f32x4){0.f, 0.f, 0.f, 0.f};

  auto compute = [&](int cur) {
    const char* ab  = smem + cur * BUF;
    const char* bbp = smem + cur * BUF + A_BYTES;
    short8 bfr[4];
    #pragma unroll
    for (int f = 0; f < 4; ++f) {
      const char* rowp = bbp + (size_t)(wn + f * 16 + lrow) * 128;
      f32x4 lo = *reinterpret_cast<const f32x4*>(rowp + pb0);
      f32x4 hi = *reinterpret_cast<const f32x4*>(rowp + (pb0 ^ 16));
      u32x4 pk;
      pk[0] = cvt_pk_bf16(lo[0], lo[1]); pk[1] = cvt_pk_bf16(lo[2], lo[3]);
      pk[2] = cvt_pk_bf16(hi[0], hi[1]); pk[3] = cvt_pk_bf16(hi[2], hi[3]);
      bfr[f] = __builtin_bit_cast(short8, pk);
    }
    #pragma unroll
    for (int i = 0; i < 8; ++i) {
      short8 afr = *reinterpret_cast<const short8*>(ab + (wm + i * 16 + lrow) * 64 + pa0);
      #pragma unroll
      for (int j = 0; j < 4; ++j)
        acc_[i][j] = __builtin_amdgcn_mfma_f32_16x16x32_bf16(afr, bfr[j], acc_[i][j], 0, 0, 0);
    }
  };

  stageA(0, 0); stageB(0, 0);
  stageA(1, 1); stageB(1, 1);
  int cur = 0, nx2 = 2;
  for (int kt = 0; kt < NTT; ++kt) {
    if (kt + 1 < NTT) asm volatile("s_waitcnt vmcnt(6)\n\ts_barrier" ::: "memory");
    else              asm volatile("s_waitcnt vmcnt(0)\n\ts_barrier" ::: "memory");
    __builtin_amdgcn_sched_barrier(0);
    if (kt + 2 < NTT) { stageA(nx2, kt + 2); stageB(nx2, kt + 2); }
    compute(cur);
    cur = (cur == 2) ? 0 : cur + 1;
    nx2 = (nx2 == 2) ? 0 : nx2 + 1;
  }

  float bv[4];
  #pragma unroll
  for (int f = 0; f < 4; ++f)
    bv[f] = bias[bbase + n0 + wn + f * 16 + lrow];

  __syncthreads();
  unsigned short* hout = (unsigned short*)smem;   // 128 KB scratch
  #pragma unroll
  for (int i = 0; i < 8; ++i) {
    const int rbase = wm + i * 16 + (lane >> 4) * 4;
    #pragma unroll
    for (int j = 0; j < 4; ++j) {
      #pragma unroll
      for (int jj = 0; jj < 4; ++jj) {
        float xv = acc_[i][j][jj] + bv[j];
        float y2 = xv * (1.5957691216057308f + 0.07135481627f * xv * xv);
        float g  = xv * __builtin_amdgcn_rcpf(1.0f + __expf(-y2));
        hout[(rbase + jj) * 256 + wn + j * 16 + lrow] = (unsigned short)(cvt_pk_bf16(g, g) & 0xFFFFu);
      }
    }
  }
  __syncthreads();
  #pragma unroll
  for (int s = 0; s < 16; ++s) {
    const int row = s * 16 + (tid >> 5);
    const int c   = (tid & 31) * 8;
    if (m0 + row < Me) {
      *reinterpret_cast<short8*>(Oh + (size_t)(tok0 + m0 + row) * NDIM + n0 + c)
        = *reinterpret_cast<const short8*>(hout + row * 256 + c);
    }
  }
}

// ======= G2: m97-EXACT pure-bf16: 128x128, 256 thr, 2-buf 32KB, __syncthreads ========
// out += h @ w2b^T + b2/KS.  A (h) and B (w2b) bf16 via gl_lds (2+2 inst/thread).
// 32 KB LDS + ~84 VGPR -> 5 blocks/CU, ~20 waves/CU: the barrier drain is covered by
// cross-block TLP (m114/m97 — the 874 TF regime). KS=2 -> 1200 blocks = 94% slot fill.
template<int NDIM, int KDIM, int NWG, int KS>
__global__ __launch_bounds__(256, 5)
void g2_gemm128b(const unsigned short* __restrict__ Ah, const unsigned short* __restrict__ Wh,
                 const float* __restrict__ bias, float* __restrict__ Of)
{
  constexpr int T_BYTES = 128 * 64;      // one bf16 128x32 tile = 8 KB
  constexpr int BUF  = 2 * T_BYTES;      // A + B = 16 KB
  constexpr int NT   = KDIM / (KS * 32);
  constexpr int NWG1 = NWG / KS;
  static_assert(NWG % 8 == 0);
  static_assert(NT >= 2);

  __shared__ __align__(16) char smem[2 * BUF];   // 32 KB

  const int tid  = threadIdx.x;
  const int braw = blockIdx.x;
  const int t = (braw & 7) * (NWG / 8) + (braw >> 3);

  const int kc    = t / NWG1;            // chunk-major: chunks segregate by XCD
  const int tt    = t % NWG1;
  const int kbase = kc * (KDIM / KS);

  // m-fastest, GN=1: all m-tiles of an expert walk one 128-col W2 panel (L2-resident)
  int m0 = 0, n0 = 0, Me = 0, tok0 = 0;
  size_t wbase = 0, bbase = 0;
  {
    int acc0 = 0;
    #pragma unroll
    for (int i = 0; i < E_NUM; ++i) {
      const int mt = cdiv_(CAPS[i], 128);        // pow2 for all caps
      const int nb = mt * (NDIM / 128);
      if (tt >= acc0 && tt < acc0 + nb) {
        const int loc = tt - acc0;
        m0   = (loc & (mt - 1)) * 128;
        n0   = (loc >> ilog2_(mt)) * 128;
        Me   = CAPS[i];
        tok0 = OFFS[i];
        wbase = (size_t)i * NDIM * KDIM;
        bbase = (size_t)i * NDIM;
      }
      acc0 += nb;
    }
  }

  const int lane = tid & 63;
  const int wv   = tid >> 6;             // 0..3
  const int wm   = (wv >> 1) * 64;
  const int wn   = (wv & 1) * 64;
  const int lrow = lane & 15;
  const int pa0  = (((lane >> 4) ^ (lane & 3)) << 4);

  const unsigned short* Abase = Ah + (size_t)(tok0 + m0) * KDIM + kbase;
  const unsigned short* Bbase = Wh + wbase + (size_t)n0 * KDIM + kbase;

  // stage one bf16 128x32 tile: 2 gl_lds16/thread (16 rows x 64B per inst per wave)
  auto stage_tile = [&](const unsigned short* base, char* dst0, int kt) {
    const unsigned short* Tg = base + kt * 32;
    #pragma unroll
    for (int j = 0; j < 2; ++j) {
      const int rbase = wv * 32 + j * 16;
      const int r     = rbase + (lane >> 2);
      const int blk   = (lane & 3) ^ (r & 3);
      gl_lds16((const void*)(Tg + (size_t)r * KDIM + blk * 8), (void*)(dst0 + rbase * 64));
    }
  };
  auto stage = [&](int buf, int kt) {
    stage_tile(Abase, smem + buf * BUF, kt);
    stage_tile(Bbase, smem + buf * BUF + T_BYTES, kt);
  };

  f32x4 acc_[4][4];
  #pragma unroll
  for (int i = 0; i < 4; ++i)
    #pragma unroll
    for (int j = 0; j < 4; ++j)
      acc_[i][j] = (f32x4){0.f, 0.f, 0.f, 0.f};

  auto compute = [&](int cur) {
    const char* ab = smem + cur * BUF;
    const char* bb = smem + cur * BUF + T_BYTES;
    short8 afr[4], bfr[4];
    #pragma unroll
    for (int f = 0; f < 4; ++f)
      afr[f] = *reinterpret_cast<const short8*>(ab + (wm + f * 16 + lrow) * 64 + pa0);
    #pragma unroll
    for (int f = 0; f < 4; ++f)
      bfr[f] = *reinterpret_cast<const short8*>(bb + (wn + f * 16 + lrow) * 64 + pa0);
    #pragma unroll
    for (int i = 0; i < 4; ++i)
      #pragma unroll
      for (int j = 0; j < 4; ++j)
        acc_[i][j] = __builtin_amdgcn_mfma_f32_16x16x32_bf16(afr[i], bfr[j], acc_[i][j], 0, 0, 0);
  };

  // m97-exact loop: double-buffer, one __syncthreads per iter (compiler drains)
  stage(0, 0);
  __syncthreads();
  for (int kt = 0; kt < NT; ++kt) {
    const int cur = kt & 1;
    if (kt + 1 < NT) stage(cur ^ 1, kt + 1);
    compute(cur);
    __syncthreads();
  }

  float bv[4];
  #pragma unroll
  for (int f = 0; f < 4; ++f)
    bv[f] = bias[bbase + n0 + wn + f * 16 + lrow];

  constexpr float BS = 1.0f / (float)KS;
  #pragma unroll
  for (int i = 0; i < 4; ++i) {
    const int rbase = wm + i * 16 + (lane >> 4) * 4;
    #pragma unroll
    for (int jj = 0; jj < 4; ++jj) {
      int grow = m0 + rbase + jj;
      if (grow < Me) {
        #pragma unroll
        for (int j = 0; j < 4; ++j) {
          float v = acc_[i][j][jj] + bv[j] * BS;
          float* p = Of + (size_t)(tok0 + grow) * NDIM + n0 + wn + j * 16 + lrow;
          if constexpr (KS > 1) unsafeAtomicAdd(p, v);
          else                  *p = v;
        }
      }
    }
  }
}

extern "C" void kernel_launch(void* const* d_in, const int* in_sizes, int n_in,
                              void* d_out, int out_size, void* d_ws, size_t ws_size,
                              hipStream_t stream)
{
  const float* x  = (const float*)d_in[0];
  const float* W1 = (const float*)d_in[1];
  const float* b1 = (const float*)d_in[2];
  const float* W2 = (const float*)d_in[3];
  const float* b2 = (const float*)d_in[4];
  float* out = (float*)d_out;

  constexpr size_t H_BYTES   = (size_t)9536 * 4096 * 2;          // 78.1 MB
  constexpr size_t XB_BYTES  = (size_t)9536 * 1024 * 2;          // 19.5 MB
  unsigned short* h   = (unsigned short*)d_ws;
  unsigned short* xb  = (unsigned short*)((char*)d_ws + H_BYTES);
  unsigned short* w2b = (unsigned short*)((char*)d_ws + H_BYTES + XB_BYTES);
  // ws requirement ~130 MB — proven available (R14/R15 passed using w2b).

  // zero d_out for split-K atomic accumulation (~8 us)
  hipMemsetAsync(d_out, 0, (size_t)out_size * sizeof(float), stream);

  // x fp32 -> bf16 (58 MB traffic, ~10 us)
  cvt_bf16_kernel<<<2048, 256, 0, stream>>>(x, xb, 9536 * 1024 / 8);

  // G1 first (L2/L3 not polluted by the W2 stream) — 624 blocks, 256^2 tiles
  g1_gemm256<4096, 1024, 2, 624><<<624, 512, 0, stream>>>(xb, W1, b1, h);

  // W2 fp32 -> bf16 (402 MB traffic, ~64 us); leaves w2b L2/L3-warm for G2
  cvt_bf16_kernel<<<2048, 256, 0, stream>>>(W2, w2b, 16 * 1024 * 4096 / 8);

  // G2: m97-structure pure-bf16, 75 m x 8 n x KS2 = 1200 blocks
  g2_gemm128b<1024, 4096, 1200, 2><<<1200, 256, 0, stream>>>(h, w2b, b2, out);
}

// Round 17
// 358.477 us; speedup vs baseline: 1.1851x; 1.1851x over previous
//
#include <hip/hip_runtime.h>
#include <math.h>

typedef __attribute__((ext_vector_type(8))) short short8;
typedef __attribute__((ext_vector_type(4))) float f32x4;
typedef __attribute__((ext_vector_type(2))) unsigned int u32x2;
typedef __attribute__((ext_vector_type(4))) unsigned int u32x4;

#define E_NUM 16
constexpr int CAPS[E_NUM] = {1024,512,1024,256,1024,512,128,1024,512,1024,256,512,1024,128,64,512};
constexpr int OFFS[E_NUM] = {0,1024,1536,2560,2816,3840,4352,4480,5504,6016,7040,7296,7808,8832,8960,9024};
constexpr int cdiv_(int a, int b){ return (a + b - 1) / b; }
constexpr int ilog2_(int v){ int l = 0; while ((1 << l) < v) ++l; return l; }

__device__ __forceinline__ unsigned int cvt_pk_bf16(float a, float b){
  unsigned int r;
  asm("v_cvt_pk_bf16_f32 %0, %1, %2" : "=v"(r) : "v"(a), "v"(b));
  return r;
}

typedef __attribute__((address_space(1))) const unsigned char gas_u8;
typedef __attribute__((address_space(3))) unsigned char las_u8;
__device__ __forceinline__ void gl_lds16(const void* g, void* l){
  __builtin_amdgcn_global_load_lds((gas_u8*)g, (las_u8*)l, 16, 0, 0);
}

// fp32 -> bf16 (RNE), 8 elems/thread, grid-stride (used for x and W2)
__global__ __launch_bounds__(256) void cvt_bf16_kernel(const float* __restrict__ x,
                                                       unsigned short* __restrict__ xb, int n8)
{
  int i = blockIdx.x * blockDim.x + threadIdx.x;
  const int stride = gridDim.x * blockDim.x;
  for (; i < n8; i += stride) {
    f32x4 a = *reinterpret_cast<const f32x4*>(x + (size_t)i * 8);
    f32x4 b = *reinterpret_cast<const f32x4*>(x + (size_t)i * 8 + 4);
    u32x2 lo, hi;
    lo[0] = cvt_pk_bf16(a[0], a[1]); lo[1] = cvt_pk_bf16(a[2], a[3]);
    hi[0] = cvt_pk_bf16(b[0], b[1]); hi[1] = cvt_pk_bf16(b[2], b[3]);
    *reinterpret_cast<u32x2*>(xb + (size_t)i * 8)     = lo;
    *reinterpret_cast<u32x2*>(xb + (size_t)i * 8 + 4) = hi;
  }
}

// ===================== G1: 256x256, 512 thr, 3-buf counted-vmcnt (FROZEN) ===========
template<int NDIM, int KDIM, int LOG_GN, int NWG>
__global__ __launch_bounds__(512, 2)
void g1_gemm256(const unsigned short* __restrict__ Ah, const float* __restrict__ W,
                const float* __restrict__ bias, unsigned short* __restrict__ Oh)
{
  constexpr int A_BYTES = 256 * 64;
  constexpr int B_BYTES = 256 * 128;
  constexpr int BUF  = A_BYTES + B_BYTES;   // 48 KB
  constexpr int GN   = 1 << LOG_GN;
  constexpr int NTT  = KDIM / 32;
  static_assert(NWG % 8 == 0);
  static_assert(NTT >= 3);

  __shared__ __align__(16) char smem[3 * BUF];   // 144 KB

  const int tid  = threadIdx.x;
  const int braw = blockIdx.x;
  const int tt = (braw & 7) * (NWG / 8) + (braw >> 3);

  int m0 = 0, n0 = 0, Me = 0, tok0 = 0;
  size_t wbase = 0, bbase = 0;
  {
    int acc0 = 0;
    #pragma unroll
    for (int i = 0; i < E_NUM; ++i) {
      const int mt  = cdiv_(CAPS[i], 256);
      const int lmt = ilog2_(mt);
      const int nb  = mt * (NDIM / 256);
      if (tt >= acc0 && tt < acc0 + nb) {
        const int loc = tt - acc0;
        const int g   = loc >> (lmt + LOG_GN);
        const int rem = loc & ((mt << LOG_GN) - 1);
        m0   = (rem >> LOG_GN) * 256;
        n0   = ((g << LOG_GN) | (rem & (GN - 1))) * 256;
        Me   = CAPS[i];
        tok0 = OFFS[i];
        wbase = (size_t)i * NDIM * KDIM;
        bbase = (size_t)i * NDIM;
      }
      acc0 += nb;
    }
  }
  const float* Wb = W + wbase;

  const int lane = tid & 63;
  const int wv   = tid >> 6;

  auto stageA = [&](int buf, int kt) {
    const unsigned short* Ag = Ah + (size_t)(tok0 + m0) * KDIM + kt * 32;
    char* dst0 = smem + buf * BUF;
    #pragma unroll
    for (int j = 0; j < 2; ++j) {
      const int rbase = j * 128 + wv * 16;
      const int r     = rbase + (lane >> 2);
      const int blk   = (lane & 3) ^ (r & 3);
      gl_lds16((const void*)(Ag + (size_t)r * KDIM + blk * 8), (void*)(dst0 + rbase * 64));
    }
  };
  auto stageB = [&](int buf, int kt) {
    const float* Bg = Wb + (size_t)n0 * KDIM + kt * 32;
    char* dst0 = smem + buf * BUF + A_BYTES;
    #pragma unroll
    for (int j = 0; j < 4; ++j) {
      const int rbase = j * 64 + wv * 8;
      const int r     = rbase + (lane >> 3);
      const int blk   = (lane & 7) ^ (r & 7);
      gl_lds16((const void*)(Bg + (size_t)r * KDIM + blk * 4), (void*)(dst0 + rbase * 128));
    }
  };

  const int wm   = (wv >> 2) * 128;
  const int wn   = (wv & 3) * 64;
  const int lrow = lane & 15;
  const int pa0  = (((lane >> 4) ^ (lane & 3)) << 4);
  const int pb0  = ((((lane >> 4) << 1) ^ (lane & 7)) << 4);

  f32x4 acc_[8][4];
  #pragma unroll
  for (int i = 0; i < 8; ++i)
    #pragma unroll
    for (int j = 0; j < 4; ++j)
      acc_[i][j] = (f32x4){0.f, 0.f, 0.f, 0.f};

  auto compute = [&](int cur) {
    const char* ab  = smem + cur * BUF;
    const char* bbp = smem + cur * BUF + A_BYTES;
    short8 bfr[4];
    #pragma unroll
    for (int f = 0; f < 4; ++f) {
      const char* rowp = bbp + (size_t)(wn + f * 16 + lrow) * 128;
      f32x4 lo = *reinterpret_cast<const f32x4*>(rowp + pb0);
      f32x4 hi = *reinterpret_cast<const f32x4*>(rowp + (pb0 ^ 16));
      u32x4 pk;
      pk[0] = cvt_pk_bf16(lo[0], lo[1]); pk[1] = cvt_pk_bf16(lo[2], lo[3]);
      pk[2] = cvt_pk_bf16(hi[0], hi[1]); pk[3] = cvt_pk_bf16(hi[2], hi[3]);
      bfr[f] = __builtin_bit_cast(short8, pk);
    }
    #pragma unroll
    for (int i = 0; i < 8; ++i) {
      short8 afr = *reinterpret_cast<const short8*>(ab + (wm + i * 16 + lrow) * 64 + pa0);
      #pragma unroll
      for (int j = 0; j < 4; ++j)
        acc_[i][j] = __builtin_amdgcn_mfma_f32_16x16x32_bf16(afr, bfr[j], acc_[i][j], 0, 0, 0);
    }
  };

  stageA(0, 0); stageB(0, 0);
  stageA(1, 1); stageB(1, 1);
  int cur = 0, nx2 = 2;
  for (int kt = 0; kt < NTT; ++kt) {
    if (kt + 1 < NTT) asm volatile("s_waitcnt vmcnt(6)\n\ts_barrier" ::: "memory");
    else              asm volatile("s_waitcnt vmcnt(0)\n\ts_barrier" ::: "memory");
    __builtin_amdgcn_sched_barrier(0);
    if (kt + 2 < NTT) { stageA(nx2, kt + 2); stageB(nx2, kt + 2); }
    compute(cur);
    cur = (cur == 2) ? 0 : cur + 1;
    nx2 = (nx2 == 2) ? 0 : nx2 + 1;
  }

  float bv[4];
  #pragma unroll
  for (int f = 0; f < 4; ++f)
    bv[f] = bias[bbase + n0 + wn + f * 16 + lrow];

  __syncthreads();
  unsigned short* hout = (unsigned short*)smem;   // 128 KB scratch
  #pragma unroll
  for (int i = 0; i < 8; ++i) {
    const int rbase = wm + i * 16 + (lane >> 4) * 4;
    #pragma unroll
    for (int j = 0; j < 4; ++j) {
      #pragma unroll
      for (int jj = 0; jj < 4; ++jj) {
        float xv = acc_[i][j][jj] + bv[j];
        float y2 = xv * (1.5957691216057308f + 0.07135481627f * xv * xv);
        float g  = xv * __builtin_amdgcn_rcpf(1.0f + __expf(-y2));
        hout[(rbase + jj) * 256 + wn + j * 16 + lrow] = (unsigned short)(cvt_pk_bf16(g, g) & 0xFFFFu);
      }
    }
  }
  __syncthreads();
  #pragma unroll
  for (int s = 0; s < 16; ++s) {
    const int row = s * 16 + (tid >> 5);
    const int c   = (tid & 31) * 8;
    if (m0 + row < Me) {
      *reinterpret_cast<short8*>(Oh + (size_t)(tok0 + m0 + row) * NDIM + n0 + c)
        = *reinterpret_cast<const short8*>(hout + row * 256 + c);
    }
  }
}

// ======= G2: 128x128, 256 thr, PURE-bf16 3-buf counted vmcnt(4) (R14-proven ~135us) ==
// out = h @ w2b^T + b2.  A (h) and B (w2b) both bf16 via gl_lds: 2+2 gl_lds16/thread
// per tile, 16 KB/buffer, 3 bufs = 48 KB -> 3 blocks/CU (12 waves). KS=1: plain
// stores, no memset/atomics. Counted vmcnt(4) = next tile's 4 gl_lds16 in flight.
template<int NDIM, int KDIM, int NWG>
__global__ __launch_bounds__(256, 3)
void g2_gemm128c(const unsigned short* __restrict__ Ah, const unsigned short* __restrict__ Wh,
                 const float* __restrict__ bias, float* __restrict__ Of)
{
  constexpr int T_BYTES = 128 * 64;      // one bf16 128x32 tile = 8 KB
  constexpr int BUF  = 2 * T_BYTES;      // A + B = 16 KB
  constexpr int NT   = KDIM / 32;        // 128
  static_assert(NWG % 8 == 0);
  static_assert(NT >= 3);

  __shared__ __align__(16) char smem[3 * BUF];   // 48 KB

  const int tid  = threadIdx.x;
  const int braw = blockIdx.x;
  const int tt = (braw & 7) * (NWG / 8) + (braw >> 3);

  // m-fastest, GN=1: all m-tiles of an expert walk one 128-col W2 panel (L2-resident)
  int m0 = 0, n0 = 0, Me = 0, tok0 = 0;
  size_t wbase = 0, bbase = 0;
  {
    int acc0 = 0;
    #pragma unroll
    for (int i = 0; i < E_NUM; ++i) {
      const int mt = cdiv_(CAPS[i], 128);        // pow2 for all caps
      const int nb = mt * (NDIM / 128);
      if (tt >= acc0 && tt < acc0 + nb) {
        const int loc = tt - acc0;
        m0   = (loc & (mt - 1)) * 128;
        n0   = (loc >> ilog2_(mt)) * 128;
        Me   = CAPS[i];
        tok0 = OFFS[i];
        wbase = (size_t)i * NDIM * KDIM;
        bbase = (size_t)i * NDIM;
      }
      acc0 += nb;
    }
  }

  const int lane = tid & 63;
  const int wv   = tid >> 6;             // 0..3
  const int wm   = (wv >> 1) * 64;
  const int wn   = (wv & 1) * 64;
  const int lrow = lane & 15;
  const int pa0  = (((lane >> 4) ^ (lane & 3)) << 4);

  const unsigned short* Abase = Ah + (size_t)(tok0 + m0) * KDIM;
  const unsigned short* Bbase = Wh + wbase + (size_t)n0 * KDIM;

  // stage one bf16 128x32 tile: 2 gl_lds16/thread (16 rows x 64B per inst per wave)
  auto stage_tile = [&](const unsigned short* base, char* dst0, int kt) {
    const unsigned short* Tg = base + kt * 32;
    #pragma unroll
    for (int j = 0; j < 2; ++j) {
      const int rbase = wv * 32 + j * 16;
      const int r     = rbase + (lane >> 2);
      const int blk   = (lane & 3) ^ (r & 3);
      gl_lds16((const void*)(Tg + (size_t)r * KDIM + blk * 8), (void*)(dst0 + rbase * 64));
    }
  };
  auto stage = [&](int buf, int kt) {
    stage_tile(Abase, smem + buf * BUF, kt);
    stage_tile(Bbase, smem + buf * BUF + T_BYTES, kt);
  };

  f32x4 acc_[4][4];
  #pragma unroll
  for (int i = 0; i < 4; ++i)
    #pragma unroll
    for (int j = 0; j < 4; ++j)
      acc_[i][j] = (f32x4){0.f, 0.f, 0.f, 0.f};

  auto compute = [&](int cur) {
    const char* ab = smem + cur * BUF;
    const char* bb = smem + cur * BUF + T_BYTES;
    short8 afr[4], bfr[4];
    #pragma unroll
    for (int f = 0; f < 4; ++f)
      afr[f] = *reinterpret_cast<const short8*>(ab + (wm + f * 16 + lrow) * 64 + pa0);
    #pragma unroll
    for (int f = 0; f < 4; ++f)
      bfr[f] = *reinterpret_cast<const short8*>(bb + (wn + f * 16 + lrow) * 64 + pa0);
    #pragma unroll
    for (int i = 0; i < 4; ++i)
      #pragma unroll
      for (int j = 0; j < 4; ++j)
        acc_[i][j] = __builtin_amdgcn_mfma_f32_16x16x32_bf16(afr[i], bfr[j], acc_[i][j], 0, 0, 0);
  };

  // 3-buf, 2-ahead, counted-vmcnt pipeline
  stage(0, 0);
  stage(1, 1);
  int cur = 0, nx2 = 2;
  for (int kt = 0; kt < NT; ++kt) {
    if (kt + 1 < NT) asm volatile("s_waitcnt vmcnt(4)\n\ts_barrier" ::: "memory");
    else             asm volatile("s_waitcnt vmcnt(0)\n\ts_barrier" ::: "memory");
    __builtin_amdgcn_sched_barrier(0);
    if (kt + 2 < NT) stage(nx2, kt + 2);
    compute(cur);
    cur = (cur == 2) ? 0 : cur + 1;
    nx2 = (nx2 == 2) ? 0 : nx2 + 1;
  }

  float bv[4];
  #pragma unroll
  for (int f = 0; f < 4; ++f)
    bv[f] = bias[bbase + n0 + wn + f * 16 + lrow];

  #pragma unroll
  for (int i = 0; i < 4; ++i) {
    const int rbase = wm + i * 16 + (lane >> 4) * 4;
    #pragma unroll
    for (int jj = 0; jj < 4; ++jj) {
      int grow = m0 + rbase + jj;
      if (grow < Me) {
        #pragma unroll
        for (int j = 0; j < 4; ++j) {
          Of[(size_t)(tok0 + grow) * NDIM + n0 + wn + j * 16 + lrow] = acc_[i][j][jj] + bv[j];
        }
      }
    }
  }
}

extern "C" void kernel_launch(void* const* d_in, const int* in_sizes, int n_in,
                              void* d_out, int out_size, void* d_ws, size_t ws_size,
                              hipStream_t stream)
{
  const float* x  = (const float*)d_in[0];
  const float* W1 = (const float*)d_in[1];
  const float* b1 = (const float*)d_in[2];
  const float* W2 = (const float*)d_in[3];
  const float* b2 = (const float*)d_in[4];
  float* out = (float*)d_out;

  constexpr size_t H_BYTES   = (size_t)9536 * 4096 * 2;          // 78.1 MB
  constexpr size_t XB_BYTES  = (size_t)9536 * 1024 * 2;          // 19.5 MB
  unsigned short* h   = (unsigned short*)d_ws;
  unsigned short* xb  = (unsigned short*)((char*)d_ws + H_BYTES);
  unsigned short* w2b = (unsigned short*)((char*)d_ws + H_BYTES + XB_BYTES);
  // ws requirement ~130 MB — proven available (R14-R16 passed using w2b).

  // x fp32 -> bf16 (58 MB traffic, ~10 us)
  cvt_bf16_kernel<<<2048, 256, 0, stream>>>(x, xb, 9536 * 1024 / 8);

  // G1 first (W2 stream not yet through L2/L3) — 624 blocks, 256^2 tiles
  g1_gemm256<4096, 1024, 2, 624><<<624, 512, 0, stream>>>(xb, W1, b1, h);

  // W2 fp32 -> bf16 (384 MB traffic, ~62 us); w2b L2/L3-warm for G2
  cvt_bf16_kernel<<<2048, 256, 0, stream>>>(W2, w2b, 16 * 1024 * 4096 / 8);

  // G2: pure-bf16 3-buf counted, 75 m x 8 n = 600 blocks, KS=1 (no memset/atomics)
  g2_gemm128c<1024, 4096, 600><<<600, 256, 0, stream>>>(h, w2b, b2, out);
}